// Round 1
// baseline (350.933 us; speedup 1.0000x reference)
//
#include <hip/hip_runtime.h>
#include <hip/hip_bf16.h>

#define B_ 4
#define S_ 2048
#define H_ 8
#define E_ 64
#define NW 4      // waves per attention block
#define QB 16     // q rows per wave
#define KT 64     // k/v tile size

typedef __attribute__((ext_vector_type(8))) short bf16x8v;
typedef __attribute__((ext_vector_type(4))) float f32x4v;

static __device__ __forceinline__ unsigned short f2bf(float f) {
    __hip_bfloat16 h = __float2bfloat16(f);
    return *reinterpret_cast<unsigned short*>(&h);
}

// ---------------------------------------------------------------------------
// Projection: q = (x@Wq + bq)/8  -> bf16 [B,H,S,E]
//             k = (x@Wk + bk)    -> bf16 [B,H,S,E]
//             v = (x@Wv + bv)    -> bf16 [B,H,E,S]  (pre-transposed)
// grid = B * S/16, block = 192 (wave 0: Q, wave 1: K, wave 2: V)
// ---------------------------------------------------------------------------
__global__ __launch_bounds__(192)
void proj_kernel(const float* __restrict__ query, const float* __restrict__ key,
                 const float* __restrict__ value,
                 const float* __restrict__ Wq, const float* __restrict__ bq,
                 const float* __restrict__ Wk, const float* __restrict__ bk,
                 const float* __restrict__ Wv, const float* __restrict__ bv,
                 __hip_bfloat16* __restrict__ qp, __hip_bfloat16* __restrict__ kp,
                 __hip_bfloat16* __restrict__ vtp)
{
    const int tid  = threadIdx.x;
    const int wave = tid >> 6;
    const int lane = tid & 63;
    const int lr   = lane & 15;    // fragment row/col index
    const int lh   = lane >> 4;    // k-slice group
    const int ntile = S_ / 16;
    const int b     = blockIdx.x / ntile;
    const int sbase = (blockIdx.x % ntile) * 16;

    const float* x    = (wave == 0) ? query : (wave == 1) ? key : value;
    const float* W    = (wave == 0) ? Wq    : (wave == 1) ? Wk  : Wv;
    const float* bias = (wave == 0) ? bq    : (wave == 1) ? bk  : bv;

    // B fragments of W: lane holds W[e = lh*8+j + 32*hf][f = cb*16+lr]
    bf16x8v wf[4][2];
#pragma unroll
    for (int cb = 0; cb < 4; ++cb)
#pragma unroll
        for (int hf = 0; hf < 2; ++hf)
#pragma unroll
            for (int j = 0; j < 8; ++j) {
                int e = lh * 8 + j + 32 * hf;
                wf[cb][hf][j] = (short)f2bf(W[e * E_ + cb * 16 + lr]);
            }
    float bvals[4];
#pragma unroll
    for (int cb = 0; cb < 4; ++cb) bvals[cb] = bias[cb * 16 + lr];

    for (int h = 0; h < H_; ++h) {
        // A fragments: lane holds x[row = sbase+lr][e = lh*8+j + 32*hf]
        const float* xrow = x + (((size_t)b * S_ + sbase + lr) * H_ + h) * E_;
        bf16x8v af[2];
#pragma unroll
        for (int hf = 0; hf < 2; ++hf)
#pragma unroll
            for (int j = 0; j < 8; ++j)
                af[hf][j] = (short)f2bf(xrow[lh * 8 + j + 32 * hf]);

#pragma unroll
        for (int cb = 0; cb < 4; ++cb) {
            f32x4v acc = {0.f, 0.f, 0.f, 0.f};
            acc = __builtin_amdgcn_mfma_f32_16x16x32_bf16(af[0], wf[cb][0], acc, 0, 0, 0);
            acc = __builtin_amdgcn_mfma_f32_16x16x32_bf16(af[1], wf[cb][1], acc, 0, 0, 0);
            // D layout: row = 4*lh + r, col = cb*16 + lr
#pragma unroll
            for (int r = 0; r < 4; ++r) {
                float v  = acc[r] + bvals[cb];
                int row  = sbase + 4 * lh + r;
                int col  = cb * 16 + lr;
                if (wave == 0) {
                    v *= 0.125f;  // fold 1/sqrt(E)
                    qp[(((size_t)b * H_ + h) * S_ + row) * E_ + col] = __float2bfloat16(v);
                } else if (wave == 1) {
                    kp[(((size_t)b * H_ + h) * S_ + row) * E_ + col] = __float2bfloat16(v);
                } else {
                    vtp[(((size_t)b * H_ + h) * E_ + col) * S_ + row] = __float2bfloat16(v);
                }
            }
        }
    }
}

// ---------------------------------------------------------------------------
// Flash attention with dropout mask.
// grid = B*H * S/(QB*NW), block = 256. Wave w owns q rows [qbase, qbase+16).
// ---------------------------------------------------------------------------
__global__ __launch_bounds__(256)
void attn_kernel(const __hip_bfloat16* __restrict__ qp,
                 const __hip_bfloat16* __restrict__ kp,
                 const __hip_bfloat16* __restrict__ vtp,
                 const int* __restrict__ mask,
                 float* __restrict__ out)
{
    __shared__ unsigned short Kt[KT * E_];       // swizzled [k][e]
    __shared__ unsigned short Vs[E_ * KT];       // swizzled [e][k]
    __shared__ unsigned short Pt[NW][16 * KT];   // swizzled [q][k], per wave

    const int tid  = threadIdx.x;
    const int wave = tid >> 6;
    const int lane = tid & 63;
    const int lr   = lane & 15;
    const int lh   = lane >> 4;
    const int nqt  = S_ / (QB * NW);              // 32
    const int bh   = blockIdx.x / nqt;            // consecutive blocks share K/V
    const int qt   = blockIdx.x % nqt;
    const int qbase = qt * (QB * NW) + wave * QB;

    // Q fragments (1/8 already folded in)
    const __hip_bfloat16* qrow = qp + ((size_t)bh * S_ + qbase + lr) * E_;
    bf16x8v aq[2];
    aq[0] = *reinterpret_cast<const bf16x8v*>(qrow + lh * 8);
    aq[1] = *reinterpret_cast<const bf16x8v*>(qrow + lh * 8 + 32);

    float m_[4], lsum[4];
    f32x4v Oa[4];
#pragma unroll
    for (int r = 0; r < 4; ++r) { m_[r] = -INFINITY; lsum[r] = 0.f; }
#pragma unroll
    for (int eb = 0; eb < 4; ++eb) Oa[eb] = {0.f, 0.f, 0.f, 0.f};

    const __hip_bfloat16* kbase_g = kp  + (size_t)bh * S_ * E_;
    const __hip_bfloat16* vbase_g = vtp + (size_t)bh * E_ * S_;
    const int* maskbase = mask + ((size_t)bh * S_ + qbase) * S_;

    char* KtB = (char*)Kt;
    char* VsB = (char*)Vs;
    char* PtB = (char*)(Pt[wave]);
    constexpr float KEEP_INV = 1.0f / 0.9f;

    for (int kt = 0; kt < S_ / KT; ++kt) {
        const int kb = kt * KT;
        __syncthreads();  // previous tile's LDS reads complete
        // stage K tile [64 k][64 e] and V tile [64 e][64 k], XOR-swizzled
#pragma unroll
        for (int i = 0; i < 2; ++i) {
            int c   = tid + i * 256;      // 512 chunks of 8 bf16
            int row = c >> 3;
            int e0  = (c & 7) * 8;
            uint4 kd = *reinterpret_cast<const uint4*>(kbase_g + (size_t)(kb + row) * E_ + e0);
            *reinterpret_cast<uint4*>(KtB + ((row * 128 + e0 * 2) ^ ((row & 7) << 4))) = kd;
            uint4 vd = *reinterpret_cast<const uint4*>(vbase_g + (size_t)row * S_ + kb + e0);
            *reinterpret_cast<uint4*>(VsB + ((row * 128 + e0 * 2) ^ ((row & 7) << 4))) = vd;
        }
        __syncthreads();

        // ---- QK^T : S[q][k], D layout row = 4*lh+r (q), col = lr (k within cb)
        f32x4v sc[4];
#pragma unroll
        for (int cb = 0; cb < 4; ++cb) {
            int kcol = cb * 16 + lr;
            bf16x8v bk0 = *reinterpret_cast<bf16x8v*>(
                KtB + ((kcol * 128 + lh * 16) ^ ((kcol & 7) << 4)));
            bf16x8v bk1 = *reinterpret_cast<bf16x8v*>(
                KtB + ((kcol * 128 + 64 + lh * 16) ^ ((kcol & 7) << 4)));
            f32x4v a = {0.f, 0.f, 0.f, 0.f};
            a = __builtin_amdgcn_mfma_f32_16x16x32_bf16(aq[0], bk0, a, 0, 0, 0);
            a = __builtin_amdgcn_mfma_f32_16x16x32_bf16(aq[1], bk1, a, 0, 0, 0);
            sc[cb] = a;
        }

        // ---- online softmax (rows 4*lh+r; reduce over k = 4 cb regs x 16 lanes)
        float p[4][4];  // [cb][r]
#pragma unroll
        for (int r = 0; r < 4; ++r) {
            float tmax = fmaxf(fmaxf(sc[0][r], sc[1][r]), fmaxf(sc[2][r], sc[3][r]));
#pragma unroll
            for (int off = 1; off < 16; off <<= 1)
                tmax = fmaxf(tmax, __shfl_xor(tmax, off));
            float newm  = fmaxf(m_[r], tmax);
            float scale = __expf(m_[r] - newm);
            m_[r] = newm;
            float rs = 0.f;
#pragma unroll
            for (int cb = 0; cb < 4; ++cb) {
                p[cb][r] = __expf(sc[cb][r] - newm);
                rs += p[cb][r];
            }
#pragma unroll
            for (int off = 1; off < 16; off <<= 1)
                rs += __shfl_xor(rs, off);
            lsum[r] = lsum[r] * scale + rs;
#pragma unroll
            for (int eb = 0; eb < 4; ++eb) Oa[eb][r] *= scale;
        }

        // ---- dropout + write P (bf16) to per-wave swizzled LDS tile
        const int* mrow = maskbase + (size_t)(4 * lh) * S_ + kb + lr;
#pragma unroll
        for (int r = 0; r < 4; ++r) {
            const int* mr = mrow + (size_t)r * S_;
            int q = 4 * lh + r;
#pragma unroll
            for (int cb = 0; cb < 4; ++cb) {
                float pk = mr[cb * 16] ? p[cb][r] * KEEP_INV : 0.f;
                *reinterpret_cast<unsigned short*>(
                    PtB + ((q * 128 + (cb * 16 + lr) * 2) ^ ((q & 7) << 4))) = f2bf(pk);
            }
        }

        // ---- PV : O[q][e] += P[q][k] * V[k][e]
#pragma unroll
        for (int mh = 0; mh < 2; ++mh) {
            int k0 = mh * 32 + lh * 8;
            bf16x8v pa = *reinterpret_cast<bf16x8v*>(
                PtB + ((lr * 128 + k0 * 2) ^ ((lr & 7) << 4)));
#pragma unroll
            for (int eb = 0; eb < 4; ++eb) {
                int e = eb * 16 + lr;
                bf16x8v vb = *reinterpret_cast<bf16x8v*>(
                    VsB + ((e * 128 + k0 * 2) ^ ((e & 7) << 4)));
                Oa[eb] = __builtin_amdgcn_mfma_f32_16x16x32_bf16(pa, vb, Oa[eb], 0, 0, 0);
            }
        }
    }

    // ---- epilogue: out[b,h,q,e] = O / lsum   (fp32 out, [B,H,S,E])
    float* orow = out + ((size_t)bh * S_ + qbase) * E_;
#pragma unroll
    for (int r = 0; r < 4; ++r) {
        float inv = 1.0f / lsum[r];
        int q = 4 * lh + r;
#pragma unroll
        for (int eb = 0; eb < 4; ++eb)
            orow[(size_t)q * E_ + eb * 16 + lr] = Oa[eb][r] * inv;
    }
}

extern "C" void kernel_launch(void* const* d_in, const int* in_sizes, int n_in,
                              void* d_out, int out_size, void* d_ws, size_t ws_size,
                              hipStream_t stream) {
    (void)in_sizes; (void)n_in; (void)out_size; (void)ws_size;
    const float* query = (const float*)d_in[0];
    const float* key   = (const float*)d_in[1];
    const float* value = (const float*)d_in[2];
    const float* Wq    = (const float*)d_in[3];
    const float* bq    = (const float*)d_in[4];
    const float* Wk    = (const float*)d_in[5];
    const float* bk    = (const float*)d_in[6];
    const float* Wv    = (const float*)d_in[7];
    const float* bv    = (const float*)d_in[8];
    const int*   mask  = (const int*)d_in[9];
    float*       out   = (float*)d_out;

    const size_t per = (size_t)B_ * H_ * S_ * E_;
    __hip_bfloat16* qp  = (__hip_bfloat16*)d_ws;
    __hip_bfloat16* kp  = qp + per;
    __hip_bfloat16* vtp = kp + per;

    proj_kernel<<<B_ * (S_ / 16), 192, 0, stream>>>(query, key, value,
                                                    Wq, bq, Wk, bk, Wv, bv,
                                                    qp, kp, vtp);
    attn_kernel<<<B_ * H_ * (S_ / (QB * NW)), 256, 0, stream>>>(qp, kp, vtp, mask, out);
}

// Round 2
// 247.319 us; speedup vs baseline: 1.4190x; 1.4190x over previous
//
#include <hip/hip_runtime.h>
#include <hip/hip_bf16.h>

#define B_ 4
#define S_ 2048
#define H_ 8
#define E_ 64
#define NW 4      // waves per attention block
#define QB 16     // q rows per wave
#define KT 64     // k/v tile size
#define NT (S_ / KT)

typedef __attribute__((ext_vector_type(8))) short bf16x8v;
typedef __attribute__((ext_vector_type(4))) float f32x4v;

static __device__ __forceinline__ unsigned short f2bf(float f) {
    __hip_bfloat16 h = __float2bfloat16(f);
    return *reinterpret_cast<unsigned short*>(&h);
}

// async global->LDS, 16B per lane; dest = wave-uniform base + lane*16
static __device__ __forceinline__ void gl_lds16(const void* g, void* lds) {
    __builtin_amdgcn_global_load_lds(
        (const __attribute__((address_space(1))) unsigned int*)g,
        (__attribute__((address_space(3))) unsigned int*)lds,
        16, 0, 0);
}

// ---------------------------------------------------------------------------
// Projection: q = (x@Wq + bq)/8  -> bf16 [B,H,S,E]
//             k = (x@Wk + bk)    -> bf16 [B,H,S,E]
//             v = (x@Wv + bv)    -> bf16 [B,H,E,S]  (pre-transposed)
// grid = B * S/16, block = 192 (wave 0: Q, wave 1: K, wave 2: V)
// ---------------------------------------------------------------------------
__global__ __launch_bounds__(192)
void proj_kernel(const float* __restrict__ query, const float* __restrict__ key,
                 const float* __restrict__ value,
                 const float* __restrict__ Wq, const float* __restrict__ bq,
                 const float* __restrict__ Wk, const float* __restrict__ bk,
                 const float* __restrict__ Wv, const float* __restrict__ bv,
                 __hip_bfloat16* __restrict__ qp, __hip_bfloat16* __restrict__ kp,
                 __hip_bfloat16* __restrict__ vtp)
{
    const int tid  = threadIdx.x;
    const int wave = tid >> 6;
    const int lane = tid & 63;
    const int lr   = lane & 15;
    const int lh   = lane >> 4;
    const int ntile = S_ / 16;
    const int b     = blockIdx.x / ntile;
    const int sbase = (blockIdx.x % ntile) * 16;

    const float* x    = (wave == 0) ? query : (wave == 1) ? key : value;
    const float* W    = (wave == 0) ? Wq    : (wave == 1) ? Wk  : Wv;
    const float* bias = (wave == 0) ? bq    : (wave == 1) ? bk  : bv;

    bf16x8v wf[4][2];
#pragma unroll
    for (int cb = 0; cb < 4; ++cb)
#pragma unroll
        for (int hf = 0; hf < 2; ++hf)
#pragma unroll
            for (int j = 0; j < 8; ++j) {
                int e = lh * 8 + j + 32 * hf;
                wf[cb][hf][j] = (short)f2bf(W[e * E_ + cb * 16 + lr]);
            }
    float bvals[4];
#pragma unroll
    for (int cb = 0; cb < 4; ++cb) bvals[cb] = bias[cb * 16 + lr];

    for (int h = 0; h < H_; ++h) {
        const float* xrow = x + (((size_t)b * S_ + sbase + lr) * H_ + h) * E_;
        bf16x8v af[2];
#pragma unroll
        for (int hf = 0; hf < 2; ++hf)
#pragma unroll
            for (int j = 0; j < 8; ++j)
                af[hf][j] = (short)f2bf(xrow[lh * 8 + j + 32 * hf]);

#pragma unroll
        for (int cb = 0; cb < 4; ++cb) {
            f32x4v acc = {0.f, 0.f, 0.f, 0.f};
            acc = __builtin_amdgcn_mfma_f32_16x16x32_bf16(af[0], wf[cb][0], acc, 0, 0, 0);
            acc = __builtin_amdgcn_mfma_f32_16x16x32_bf16(af[1], wf[cb][1], acc, 0, 0, 0);
#pragma unroll
            for (int r = 0; r < 4; ++r) {
                float v  = acc[r] + bvals[cb];
                int row  = sbase + 4 * lh + r;
                int col  = cb * 16 + lr;
                if (wave == 0) {
                    v *= 0.125f;
                    qp[(((size_t)b * H_ + h) * S_ + row) * E_ + col] = __float2bfloat16(v);
                } else if (wave == 1) {
                    kp[(((size_t)b * H_ + h) * S_ + row) * E_ + col] = __float2bfloat16(v);
                } else {
                    vtp[(((size_t)b * H_ + h) * E_ + col) * S_ + row] = __float2bfloat16(v);
                }
            }
        }
    }
}

// ---------------------------------------------------------------------------
// Flash attention, software-pipelined:
//  - K/V double-buffered in LDS, staged via global_load_lds with
//    pre-swizzled global source (linear LDS dest, XOR-swizzled image)
//  - dropout mask prefetched one tile ahead into registers (int4 x4/lane),
//    applied at PV-read; keep-scale folded into epilogue
//  - one __syncthreads per tile
// grid = B*H * S/(QB*NW), block = 256
// ---------------------------------------------------------------------------
__global__ __launch_bounds__(256)
void attn_kernel(const __hip_bfloat16* __restrict__ qp,
                 const __hip_bfloat16* __restrict__ kp,
                 const __hip_bfloat16* __restrict__ vtp,
                 const int* __restrict__ mask,
                 float* __restrict__ out)
{
    __shared__ unsigned short Kt[2][KT * E_];    // swizzled [k][e], dbuf
    __shared__ unsigned short Vs[2][KT * E_];    // swizzled [e][k], dbuf
    __shared__ unsigned short Pt[NW][16 * KT];   // swizzled [q][k], per wave

    const int tid  = threadIdx.x;
    const int wave = tid >> 6;
    const int lane = tid & 63;
    const int lr   = lane & 15;
    const int lh   = lane >> 4;
    const int nqt  = S_ / (QB * NW);
    const int bh   = blockIdx.x / nqt;
    const int qt   = blockIdx.x % nqt;
    const int qbase = qt * (QB * NW) + wave * QB;

    // Q fragments (1/8 already folded in)
    const __hip_bfloat16* qrow = qp + ((size_t)bh * S_ + qbase + lr) * E_;
    bf16x8v aq[2];
    aq[0] = *reinterpret_cast<const bf16x8v*>(qrow + lh * 8);
    aq[1] = *reinterpret_cast<const bf16x8v*>(qrow + lh * 8 + 32);

    float m_[4], lsum[4];
    f32x4v Oa[4];
#pragma unroll
    for (int r = 0; r < 4; ++r) { m_[r] = -INFINITY; lsum[r] = 0.f; }
#pragma unroll
    for (int eb = 0; eb < 4; ++eb) Oa[eb] = {0.f, 0.f, 0.f, 0.f};

    const char* kgb = (const char*)(kp  + (size_t)bh * S_ * E_);
    const char* vgb = (const char*)(vtp + (size_t)bh * E_ * S_);
    const int*  mlane = mask + ((size_t)bh * S_ + qbase + lr) * S_ + lh * 8;

    // staging invariants: wave w stages rows [w*16, w*16+16) of each tile.
    // linear LDS dest; source column pre-XOR'd so the LDS image matches the
    // (row*128 + col2) ^ ((row&7)<<4) swizzle used on the read side.
    const int rowA = wave * 16 + (lane >> 3);
    const int rowB = rowA + 8;
    const int e2   = (((lane & 7) ^ (lane >> 3)) << 4);
    const size_t koffA = (size_t)rowA * 128 + e2;        // + kb*128
    const size_t koffB = (size_t)rowB * 128 + e2;
    const size_t voffA = (size_t)rowA * (S_ * 2) + e2;   // + kb*2
    const size_t voffB = (size_t)rowB * (S_ * 2) + e2;

    char* PtB = (char*)(Pt[wave]);
    constexpr float KEEP_INV = 1.0f / 0.9f;

    // ---- prologue: stage tile 0 into buf 0; prefetch mask tile 0
    {
        char* kd = (char*)(Kt[0]) + wave * 2048;
        char* vd = (char*)(Vs[0]) + wave * 2048;
        gl_lds16(kgb + koffA, kd);
        gl_lds16(kgb + koffB, kd + 1024);
        gl_lds16(vgb + voffA, vd);
        gl_lds16(vgb + voffB, vd + 1024);
    }
    int4 mnx[4];
    {
        const int* mp = mlane;            // kb = 0
        mnx[0] = *reinterpret_cast<const int4*>(mp);
        mnx[1] = *reinterpret_cast<const int4*>(mp + 4);
        mnx[2] = *reinterpret_cast<const int4*>(mp + 32);
        mnx[3] = *reinterpret_cast<const int4*>(mp + 36);
    }
    __syncthreads();

    for (int kt = 0; kt < NT; ++kt) {
        const int kb  = kt * KT;
        const int cur = kt & 1;

        // ---- issue staging for next tile into the other buffer (async)
        if (kt + 1 < NT) {
            const size_t kadd = (size_t)(kb + KT) * 128;
            const size_t vadd = (size_t)(kb + KT) * 2;
            char* kd = (char*)(Kt[cur ^ 1]) + wave * 2048;
            char* vd = (char*)(Vs[cur ^ 1]) + wave * 2048;
            gl_lds16(kgb + kadd + koffA, kd);
            gl_lds16(kgb + kadd + koffB, kd + 1024);
            gl_lds16(vgb + vadd + voffA, vd);
            gl_lds16(vgb + vadd + voffB, vd + 1024);
        }
        // ---- rotate mask pipeline; prefetch next tile's mask
        int4 mcur[4];
#pragma unroll
        for (int i = 0; i < 4; ++i) mcur[i] = mnx[i];
        if (kt + 1 < NT) {
            const int* mp = mlane + kb + KT;
            mnx[0] = *reinterpret_cast<const int4*>(mp);
            mnx[1] = *reinterpret_cast<const int4*>(mp + 4);
            mnx[2] = *reinterpret_cast<const int4*>(mp + 32);
            mnx[3] = *reinterpret_cast<const int4*>(mp + 36);
        }

        char* KtB = (char*)(Kt[cur]);
        char* VsB = (char*)(Vs[cur]);

        // ---- QK^T : D layout row = 4*lh+r (q), col = lr (k within cb)
        f32x4v sc[4];
#pragma unroll
        for (int cb = 0; cb < 4; ++cb) {
            int kcol = cb * 16 + lr;
            bf16x8v bk0 = *reinterpret_cast<bf16x8v*>(
                KtB + ((kcol * 128 + lh * 16) ^ ((kcol & 7) << 4)));
            bf16x8v bk1 = *reinterpret_cast<bf16x8v*>(
                KtB + ((kcol * 128 + 64 + lh * 16) ^ ((kcol & 7) << 4)));
            f32x4v a = {0.f, 0.f, 0.f, 0.f};
            a = __builtin_amdgcn_mfma_f32_16x16x32_bf16(aq[0], bk0, a, 0, 0, 0);
            a = __builtin_amdgcn_mfma_f32_16x16x32_bf16(aq[1], bk1, a, 0, 0, 0);
            sc[cb] = a;
        }

        // ---- online softmax (pre-dropout, as in the reference)
        float p[4][4];
#pragma unroll
        for (int r = 0; r < 4; ++r) {
            float tmax = fmaxf(fmaxf(sc[0][r], sc[1][r]), fmaxf(sc[2][r], sc[3][r]));
#pragma unroll
            for (int off = 1; off < 16; off <<= 1)
                tmax = fmaxf(tmax, __shfl_xor(tmax, off));
            float newm  = fmaxf(m_[r], tmax);
            float scale = __expf(m_[r] - newm);
            m_[r] = newm;
            float rs = 0.f;
#pragma unroll
            for (int cb = 0; cb < 4; ++cb) {
                p[cb][r] = __expf(sc[cb][r] - newm);
                rs += p[cb][r];
            }
#pragma unroll
            for (int off = 1; off < 16; off <<= 1)
                rs += __shfl_xor(rs, off);
            lsum[r] = lsum[r] * scale + rs;
#pragma unroll
            for (int eb = 0; eb < 4; ++eb) Oa[eb][r] *= scale;
        }

        // ---- write raw P (bf16) to per-wave swizzled LDS tile
#pragma unroll
        for (int r = 0; r < 4; ++r) {
            int q = 4 * lh + r;
#pragma unroll
            for (int cb = 0; cb < 4; ++cb) {
                *reinterpret_cast<unsigned short*>(
                    PtB + ((q * 128 + (cb * 16 + lr) * 2) ^ ((q & 7) << 4))) =
                    f2bf(p[cb][r]);
            }
        }

        // ---- PV with dropout applied on the A-fragment (8 consecutive k/lane)
#pragma unroll
        for (int mh = 0; mh < 2; ++mh) {
            int k0 = mh * 32 + lh * 8;
            bf16x8v pa = *reinterpret_cast<bf16x8v*>(
                PtB + ((lr * 128 + k0 * 2) ^ ((lr & 7) << 4)));
            int4 m0 = mcur[mh * 2];
            int4 m1 = mcur[mh * 2 + 1];
            pa[0] = m0.x ? pa[0] : (short)0;
            pa[1] = m0.y ? pa[1] : (short)0;
            pa[2] = m0.z ? pa[2] : (short)0;
            pa[3] = m0.w ? pa[3] : (short)0;
            pa[4] = m1.x ? pa[4] : (short)0;
            pa[5] = m1.y ? pa[5] : (short)0;
            pa[6] = m1.z ? pa[6] : (short)0;
            pa[7] = m1.w ? pa[7] : (short)0;
#pragma unroll
            for (int eb = 0; eb < 4; ++eb) {
                int e = eb * 16 + lr;
                bf16x8v vb = *reinterpret_cast<bf16x8v*>(
                    VsB + ((e * 128 + k0 * 2) ^ ((e & 7) << 4)));
                Oa[eb] = __builtin_amdgcn_mfma_f32_16x16x32_bf16(pa, vb, Oa[eb], 0, 0, 0);
            }
        }

        __syncthreads();   // drains vmcnt(0): next tile's staging is landed
    }

    // ---- epilogue: out = O * (1/0.9) / lsum   (fp32, [B,H,S,E])
    float* orow = out + ((size_t)bh * S_ + qbase) * E_;
#pragma unroll
    for (int r = 0; r < 4; ++r) {
        float inv = KEEP_INV / lsum[r];
        int q = 4 * lh + r;
#pragma unroll
        for (int eb = 0; eb < 4; ++eb)
            orow[(size_t)q * E_ + eb * 16 + lr] = Oa[eb][r] * inv;
    }
}

extern "C" void kernel_launch(void* const* d_in, const int* in_sizes, int n_in,
                              void* d_out, int out_size, void* d_ws, size_t ws_size,
                              hipStream_t stream) {
    (void)in_sizes; (void)n_in; (void)out_size; (void)ws_size;
    const float* query = (const float*)d_in[0];
    const float* key   = (const float*)d_in[1];
    const float* value = (const float*)d_in[2];
    const float* Wq    = (const float*)d_in[3];
    const float* bq    = (const float*)d_in[4];
    const float* Wk    = (const float*)d_in[5];
    const float* bk    = (const float*)d_in[6];
    const float* Wv    = (const float*)d_in[7];
    const float* bv    = (const float*)d_in[8];
    const int*   mask  = (const int*)d_in[9];
    float*       out   = (float*)d_out;

    const size_t per = (size_t)B_ * H_ * S_ * E_;
    __hip_bfloat16* qp  = (__hip_bfloat16*)d_ws;
    __hip_bfloat16* kp  = qp + per;
    __hip_bfloat16* vtp = kp + per;

    proj_kernel<<<B_ * (S_ / 16), 192, 0, stream>>>(query, key, value,
                                                    Wq, bq, Wk, bk, Wv, bv,
                                                    qp, kp, vtp);
    attn_kernel<<<B_ * H_ * (S_ / (QB * NW)), 256, 0, stream>>>(qp, kp, vtp, mask, out);
}